// Round 15
// baseline (332.024 us; speedup 1.0000x reference)
//
#include <hip/hip_runtime.h>

#define D 128            // D_IN == D_OUT
#define BSHIFT 7         // 128 dst-nodes per bucket
#define BNODES 128
#define BMASK 127
#define NB_MAX 1024      // max buckets; src<2^17 so (src<<7) fits in 24 bits
#define STRIDE 2944      // bucket capacity: mean 2046 + ~20 sigma (uniform dst)
#define BIN_CHUNK 4096   // edges per bin block
#define GP_ROWS 64
#define GLDP 132

typedef unsigned int uint;
typedef __attribute__((ext_vector_type(8))) short bf16x8;
typedef __attribute__((ext_vector_type(4))) float f32x4;

__device__ inline uint bf16_rne(float x) {
    uint u = __float_as_uint(x);
    return (u + 0x7fffu + ((u >> 16) & 1u)) >> 16;
}
__device__ inline uint pack2(float lo, float hi) {
    return bf16_rne(lo) | (bf16_rne(hi) << 16);
}

// ---- Stage 0: init — block 0 zeroes bucket_cur, block 1 packs W ----
__global__ void __launch_bounds__(256) init_kernel(int* __restrict__ bucket_cur,
                                                   const float* __restrict__ W,
                                                   uint4* __restrict__ wpack) {
    int t = threadIdx.x;
    if (blockIdx.x == 0) {
        for (int j = t; j < NB_MAX; j += 256) bucket_cur[j] = 0;
    } else {
        for (int idx = t; idx < 2048; idx += 256) {
            int lane = idx & 63;
            int ks = (idx >> 6) & 3;
            int ct = idx >> 8;
            int col = ct * 16 + (lane & 15);
            int k0 = ks * 32 + (lane >> 4) * 8;
            uint4 u;
            u.x = pack2(W[(k0 + 0) * D + col], W[(k0 + 1) * D + col]);
            u.y = pack2(W[(k0 + 2) * D + col], W[(k0 + 3) * D + col]);
            u.z = pack2(W[(k0 + 4) * D + col], W[(k0 + 5) * D + col]);
            u.w = pack2(W[(k0 + 6) * D + col], W[(k0 + 7) * D + col]);
            wpack[idx] = u;
        }
    }
}

// ---- Stage 1 (mega): blocks [0,nchunks) bin edges; the rest compute
//      g32_raw = bf16(feat @ W), stored SLICE-MAJOR: 8 column-slices of
//      16 cols (8 uints); slice cg at g32[cg*P + node*8 + w], P = n*8.
//      Each slice is 3.2 MB -> fits one XCD's 4 MB L2. ----
__global__ void __launch_bounds__(256) mega_kernel(
        const int* __restrict__ src, const int* __restrict__ dst,
        int* __restrict__ bucket_cur, uint* __restrict__ binned,
        const float* __restrict__ feat, const uint4* __restrict__ wpack,
        uint* __restrict__ g32, int n_edges, int nchunks, int n) {
    __shared__ float As[GP_ROWS][GLDP];  // 33 KB (bin path aliases it)
    int t = threadIdx.x;

    if (blockIdx.x < (uint)nchunks) {  // ---- bin path ----
        int* h = (int*)&As[0][0];
        int* base = h + NB_MAX;
        long long e0 = (long long)blockIdx.x * BIN_CHUNK;
        for (int j = t; j < NB_MAX; j += 256) h[j] = 0;
        __syncthreads();

        int d[16], s[16];
#pragma unroll
        for (int k = 0; k < 16; ++k) {
            long long idx = e0 + k * 256 + t;
            if (idx < n_edges) {
                d[k] = dst[idx];
                s[k] = src[idx];
                atomicAdd(&h[d[k] >> BSHIFT], 1);
            } else {
                d[k] = -1;
            }
        }
        __syncthreads();
        for (int j = t; j < NB_MAX; j += 256) {
            int c = h[j];
            base[j] = c ? atomicAdd(&bucket_cur[j], c) : 0;
            h[j] = 0;  // reuse as rank counter
        }
        __syncthreads();
#pragma unroll
        for (int k = 0; k < 16; ++k) {
            if (d[k] >= 0) {
                int b = d[k] >> BSHIFT;
                int r = base[b] + atomicAdd(&h[b], 1);
                if (r < STRIDE)
                    binned[(size_t)b * STRIDE + r] =
                        ((uint)s[k] << BSHIFT) | (uint)(d[k] & BMASK);
            }
        }
        return;
    }

    // ---- gemm path: raw feat @ W -> bf16 g32 slices ----
    int lane = t & 63;
    int w = t >> 6;
    int r0 = (blockIdx.x - nchunks) * GP_ROWS;
    size_t P = (size_t)n * 8;

    for (int idx = t; idx < GP_ROWS * 32; idx += 256) {
        int row = idx >> 5;
        int p = idx & 31;
        int gr = r0 + row;
        if (gr >= n) gr = n - 1;
        float4 f = *(const float4*)(feat + (size_t)gr * D + p * 4);
        *(float4*)&As[row][p * 4] = f;
    }
    __syncthreads();

    int c = lane & 15;
    int g = lane >> 4;
    int rbase = w * 16;

    uint4 afr[4];
#pragma unroll
    for (int ks = 0; ks < 4; ++ks) {
        const float* ap = &As[rbase + c][ks * 32 + g * 8];
        float4 f0 = *(const float4*)ap;
        float4 f1 = *(const float4*)(ap + 4);
        afr[ks].x = pack2(f0.x, f0.y);
        afr[ks].y = pack2(f0.z, f0.w);
        afr[ks].z = pack2(f1.x, f1.y);
        afr[ks].w = pack2(f1.z, f1.w);
    }

#pragma unroll
    for (int ct = 0; ct < 8; ++ct) {
        f32x4 acc = {0.f, 0.f, 0.f, 0.f};
#pragma unroll
        for (int ks = 0; ks < 4; ++ks) {
            uint4 bu = wpack[(ct * 4 + ks) * 64 + lane];
            acc = __builtin_amdgcn_mfma_f32_16x16x32_bf16(
                *(bf16x8*)&afr[ks], *(bf16x8*)&bu, acc, 0, 0, 0);
        }
        // D layout: row = g*4+r, col = ct*16+c. Wave-private LDS rows.
#pragma unroll
        for (int r = 0; r < 4; ++r)
            As[rbase + g * 4 + r][ct * 16 + c] = acc[r];
    }

    // pack to bf16, slice-major: j = lane (const per lane), cg=j>>3, w=j&7
    int cg = lane >> 3;
    int wch = lane & 7;
    for (int idx = lane; idx < 16 * 64; idx += 64) {
        int row = idx >> 6;
        int gr = r0 + rbase + row;
        if (gr < n) {
            uint vpk = pack2(As[rbase + row][2 * lane],
                             As[rbase + row][2 * lane + 1]);
            g32[(size_t)cg * P + (size_t)gr * 8 + wch] = vpk;
        }
    }
}

// ---- Stage 2: per-bucket CSR sort + deg/norm/row_start (LDS-staged) ----
__global__ void __launch_bounds__(256) fill2_kernel(
        const int* __restrict__ bucket_cur, uint* __restrict__ csr,
        int* __restrict__ row_start, int* __restrict__ degp,
        float* __restrict__ norm, int n_nodes) {
    __shared__ uint sbin[STRIDE];  // 11.5 KB
    __shared__ int deg[BNODES];
    __shared__ int rs[BNODES];
    __shared__ int cur[BNODES];
    int b = blockIdx.x;
    int t = threadIdx.x;
    int cnt = bucket_cur[b];
    if (cnt > STRIDE) cnt = STRIDE;
    size_t gbase = (size_t)b * STRIDE;

    for (int k = t; k < cnt; k += 256) sbin[k] = csr[gbase + k];
    if (t < BNODES) deg[t] = 0;
    __syncthreads();
    for (int k = t; k < cnt; k += 256) atomicAdd(&deg[sbin[k] & BMASK], 1);
    __syncthreads();

    int v = 0;
    if (t < BNODES) {
        v = deg[t];
        rs[t] = v;
    }
    __syncthreads();
    for (int o = 1; o < BNODES; o <<= 1) {
        int a = (t < BNODES && t >= o) ? rs[t - o] : 0;
        __syncthreads();
        if (t < BNODES) rs[t] += a;
        __syncthreads();
    }
    if (t < BNODES) {
        int excl = rs[t] - v;
        rs[t] = excl;
        cur[t] = 0;
        int node = b * BNODES + t;
        if (node < n_nodes) {
            row_start[node] = (int)gbase + excl;
            degp[node] = v;
            norm[node] = rsqrtf(fmaxf((float)v, 1.0f));
        }
    }
    __syncthreads();

    for (int k = t; k < cnt; k += 256) {
        uint p = sbin[k];
        int dl = p & BMASK;
        int r = atomicAdd(&cur[dl], 1);
        csr[gbase + rs[dl] + r] = p >> BSHIFT;  // plain src index
    }
}

// ---- Stage 3: XCD-sliced gather ----
// Block (cg = bid&7, node-quad = bid>>3): wave w handles node q*4+w, reading
// ONLY slice cg (3.2 MB, resident in XCD cg's L2 via blockIdx round-robin).
// Lane: edge slot g2 = lane>>3 (8 edges/round), chunk c2 = lane&7 (2 cols).
// out writes + csr reads are nontemporal to protect slice residency.
__global__ void __launch_bounds__(256) gather_out_kernel(
        const uint* __restrict__ g32, const uint* __restrict__ csr,
        const int* __restrict__ row_start, const int* __restrict__ degp,
        const float* __restrict__ norm, const float* __restrict__ bias,
        float* __restrict__ out, int n) {
    int lane = threadIdx.x & 63;
    int wid = threadIdx.x >> 6;
    int cg = blockIdx.x & 7;
    int i = (blockIdx.x >> 3) * 4 + wid;
    if (i >= n) return;
    int g2 = lane >> 3;
    int c2 = lane & 7;
    size_t P = (size_t)n * 8;
    const uint* slice = g32 + (size_t)cg * P;

    int beg = row_start[i];
    int dv = degp[i];
    int end = beg + dv;
    float a0 = 0.f, a1 = 0.f;

    for (int base = beg; base < end; base += 64) {
        int nk = end - base;
        if (nk > 64) nk = 64;
        int epre = (base + lane < end)
                       ? (int)__builtin_nontemporal_load(csr + base + lane)
                       : 0;
        float npre = norm[epre];  // 400KB, L2-hot everywhere
        int k = 0;
        int kfull = nk & ~15;
        for (; k < kfull; k += 16) {  // 16 edges: 2 loads in flight
            int s0 = __shfl(epre, k + g2, 64);
            float nm0 = __shfl(npre, k + g2, 64);
            int s1 = __shfl(epre, k + 8 + g2, 64);
            float nm1 = __shfl(npre, k + 8 + g2, 64);
            uint u0 = slice[(size_t)s0 * 8 + c2];
            uint u1 = slice[(size_t)s1 * 8 + c2];
            a0 += __uint_as_float(u0 << 16) * nm0;
            a1 += __uint_as_float(u0 & 0xffff0000u) * nm0;
            a0 += __uint_as_float(u1 << 16) * nm1;
            a1 += __uint_as_float(u1 & 0xffff0000u) * nm1;
        }
        if (k < nk) {  // tail <16 edges: 2 predicated rounds
            int e0 = k + g2;
            int e1 = k + 8 + g2;
            int s0 = __shfl(epre, e0 & 63, 64);
            float nm0 = __shfl(npre, e0 & 63, 64);
            int s1 = __shfl(epre, e1 & 63, 64);
            float nm1 = __shfl(npre, e1 & 63, 64);
            uint u0 = (e0 < nk) ? slice[(size_t)s0 * 8 + c2] : 0u;
            uint u1 = (e1 < nk) ? slice[(size_t)s1 * 8 + c2] : 0u;
            a0 += __uint_as_float(u0 << 16) * nm0;
            a1 += __uint_as_float(u0 & 0xffff0000u) * nm0;
            a0 += __uint_as_float(u1 << 16) * nm1;
            a1 += __uint_as_float(u1 & 0xffff0000u) * nm1;
        }
    }

    // reduce over the 8 edge slots (xor 8/16/32 keeps c2)
    a0 += __shfl_xor(a0, 8, 64);
    a0 += __shfl_xor(a0, 16, 64);
    a0 += __shfl_xor(a0, 32, 64);
    a1 += __shfl_xor(a1, 8, 64);
    a1 += __shfl_xor(a1, 16, 64);
    a1 += __shfl_xor(a1, 32, 64);

    if (g2 == 0) {
        float nrm = rsqrtf(fmaxf((float)dv, 1.0f));
        const float2 bv = *(const float2*)(bias + cg * 16 + 2 * c2);
        float* p = out + (size_t)i * D + cg * 16 + 2 * c2;
        __builtin_nontemporal_store(a0 * nrm + bv.x, p);
        __builtin_nontemporal_store(a1 * nrm + bv.y, p + 1);
    }
}

extern "C" void kernel_launch(void* const* d_in, const int* in_sizes, int n_in,
                              void* d_out, int out_size, void* d_ws, size_t ws_size,
                              hipStream_t stream) {
    const float* feat   = (const float*)d_in[0];
    const float* weight = (const float*)d_in[1];
    const float* bias   = (const float*)d_in[2];
    const int*   src    = (const int*)d_in[3];
    const int*   dst    = (const int*)d_in[4];
    float* out = (float*)d_out;

    int n_nodes = in_sizes[0] / D;
    int n_edges = in_sizes[3];
    int nb = (n_nodes + BNODES - 1) >> BSHIFT;               // 782 buckets
    int nchunks = (n_edges + BIN_CHUNK - 1) / BIN_CHUNK;     // 391
    int ngemm = (n_nodes + GP_ROWS - 1) / GP_ROWS;           // 1563

    // workspace (4B elems): norm | deg | row_start | bucket_cur | csr | g32 | wpack
    float* norm       = (float*)d_ws;                    // n
    int*   degp       = (int*)(norm + n_nodes);          // n
    int*   row_start  = degp + n_nodes;                  // n
    int*   bucket_cur = row_start + n_nodes;             // NB_MAX
    uint*  csr        = (uint*)(bucket_cur + NB_MAX);    // nb*STRIDE (~9.2 MB)
    uint*  g32        = csr + (size_t)nb * STRIDE;       // 64n (25.6 MB, sliced)
    uint4* wpack      = (uint4*)(g32 + (size_t)n_nodes * 64);  // 32 KB

    init_kernel<<<2, 256, 0, stream>>>(bucket_cur, weight, wpack);
    mega_kernel<<<nchunks + ngemm, 256, 0, stream>>>(
        src, dst, bucket_cur, csr, feat, wpack, g32, n_edges, nchunks, n_nodes);
    fill2_kernel<<<nb, 256, 0, stream>>>(bucket_cur, csr, row_start, degp, norm,
                                         n_nodes);
    gather_out_kernel<<<((n_nodes + 3) / 4) * 8, 256, 0, stream>>>(
        g32, csr, row_start, degp, norm, bias, out, n_nodes);
}

// Round 16
// 118.780 us; speedup vs baseline: 2.7953x; 2.7953x over previous
//
#include <hip/hip_runtime.h>

#define D 128            // D_IN == D_OUT
#define BSHIFT 7         // 128 dst-nodes per bucket
#define BNODES 128
#define BMASK 127
#define NB_MAX 1024      // max buckets; src<2^17 so (src<<7) fits in 24 bits
#define STRIDE 2944      // bucket capacity: mean 2046 + ~20 sigma (uniform dst)
#define BIN_CHUNK 2048   // edges per bin block (8-deep chain, 782 blocks)
#define GP_ROWS 64
#define GLDP 132

typedef unsigned int uint;
typedef __attribute__((ext_vector_type(8))) short bf16x8;
typedef __attribute__((ext_vector_type(4))) float f32x4;

__device__ inline uint bf16_rne(float x) {
    uint u = __float_as_uint(x);
    return (u + 0x7fffu + ((u >> 16) & 1u)) >> 16;
}
__device__ inline uint pack2(float lo, float hi) {
    return bf16_rne(lo) | (bf16_rne(hi) << 16);
}

// ---- Stage 0: init — block 0 zeroes bucket_cur, block 1 packs W ----
__global__ void __launch_bounds__(256) init_kernel(int* __restrict__ bucket_cur,
                                                   const float* __restrict__ W,
                                                   uint4* __restrict__ wpack) {
    int t = threadIdx.x;
    if (blockIdx.x == 0) {
        for (int j = t; j < NB_MAX; j += 256) bucket_cur[j] = 0;
    } else {
        for (int idx = t; idx < 2048; idx += 256) {
            int lane = idx & 63;
            int ks = (idx >> 6) & 3;
            int ct = idx >> 8;
            int col = ct * 16 + (lane & 15);
            int k0 = ks * 32 + (lane >> 4) * 8;
            uint4 u;
            u.x = pack2(W[(k0 + 0) * D + col], W[(k0 + 1) * D + col]);
            u.y = pack2(W[(k0 + 2) * D + col], W[(k0 + 3) * D + col]);
            u.z = pack2(W[(k0 + 4) * D + col], W[(k0 + 5) * D + col]);
            u.w = pack2(W[(k0 + 6) * D + col], W[(k0 + 7) * D + col]);
            wpack[idx] = u;
        }
    }
}

// ---- Stage 1 (mega): bin blocks interleaved every 3rd blockIdx with gemm
//      tile blocks, so the stream/MFMA gemm work covers the latency-bound
//      LDS-atomic bin work across the whole dispatch window. ----
__global__ void __launch_bounds__(256) mega_kernel(
        const int* __restrict__ src, const int* __restrict__ dst,
        int* __restrict__ bucket_cur, uint* __restrict__ binned,
        const float* __restrict__ feat, const uint4* __restrict__ wpack,
        uint* __restrict__ g32, int n_edges, int nchunks, int ngemm, int n) {
    __shared__ float As[GP_ROWS][GLDP];  // 33 KB (bin path aliases it)
    int t = threadIdx.x;
    int bidx = blockIdx.x;
    bool isBin = ((bidx % 3) == 0) && (bidx / 3 < nchunks);

    if (isBin) {  // ---- bin path: chunk = bidx/3 ----
        int* h = (int*)&As[0][0];
        int* base = h + NB_MAX;
        long long e0 = (long long)(bidx / 3) * BIN_CHUNK;
        for (int j = t; j < NB_MAX; j += 256) h[j] = 0;
        __syncthreads();

        int d[8], s[8];
#pragma unroll
        for (int k = 0; k < 8; ++k) {
            long long idx = e0 + k * 256 + t;
            if (idx < n_edges) {
                d[k] = dst[idx];
                s[k] = src[idx];
                atomicAdd(&h[d[k] >> BSHIFT], 1);
            } else {
                d[k] = -1;
            }
        }
        __syncthreads();
        for (int j = t; j < NB_MAX; j += 256) {
            int c = h[j];
            base[j] = c ? atomicAdd(&bucket_cur[j], c) : 0;
            h[j] = 0;  // reuse as rank counter
        }
        __syncthreads();
#pragma unroll
        for (int k = 0; k < 8; ++k) {
            if (d[k] >= 0) {
                int b = d[k] >> BSHIFT;
                int r = base[b] + atomicAdd(&h[b], 1);
                if (r < STRIDE)
                    binned[(size_t)b * STRIDE + r] =
                        ((uint)s[k] << BSHIFT) | (uint)(d[k] & BMASK);
            }
        }
        return;
    }

    // ---- gemm path: raw feat @ W -> bf16 g32 ----
    int binsBefore = (bidx + 2) / 3;
    if (binsBefore > nchunks) binsBefore = nchunks;
    int tile = bidx - binsBefore;
    if (tile >= ngemm) return;
    int lane = t & 63;
    int w = t >> 6;
    int r0 = tile * GP_ROWS;

    for (int idx = t; idx < GP_ROWS * 32; idx += 256) {
        int row = idx >> 5;
        int p = idx & 31;
        int gr = r0 + row;
        if (gr >= n) gr = n - 1;
        float4 f = *(const float4*)(feat + (size_t)gr * D + p * 4);
        *(float4*)&As[row][p * 4] = f;
    }
    __syncthreads();

    int c = lane & 15;
    int g = lane >> 4;
    int rbase = w * 16;

    uint4 afr[4];
#pragma unroll
    for (int ks = 0; ks < 4; ++ks) {
        const float* ap = &As[rbase + c][ks * 32 + g * 8];
        float4 f0 = *(const float4*)ap;
        float4 f1 = *(const float4*)(ap + 4);
        afr[ks].x = pack2(f0.x, f0.y);
        afr[ks].y = pack2(f0.z, f0.w);
        afr[ks].z = pack2(f1.x, f1.y);
        afr[ks].w = pack2(f1.z, f1.w);
    }

#pragma unroll
    for (int ct = 0; ct < 8; ++ct) {
        f32x4 acc = {0.f, 0.f, 0.f, 0.f};
#pragma unroll
        for (int ks = 0; ks < 4; ++ks) {
            uint4 bu = wpack[(ct * 4 + ks) * 64 + lane];
            acc = __builtin_amdgcn_mfma_f32_16x16x32_bf16(
                *(bf16x8*)&afr[ks], *(bf16x8*)&bu, acc, 0, 0, 0);
        }
        // D layout: row = g*4+r, col = ct*16+c. Wave-private LDS rows.
#pragma unroll
        for (int r = 0; r < 4; ++r)
            As[rbase + g * 4 + r][ct * 16 + c] = acc[r];
    }

    for (int idx = lane; idx < 16 * 64; idx += 64) {
        int row = idx >> 6;
        int j = idx & 63;
        int gr = r0 + rbase + row;
        if (gr < n) {
            uint vpk = pack2(As[rbase + row][2 * j], As[rbase + row][2 * j + 1]);
            g32[(size_t)gr * 64 + j] = vpk;
        }
    }
}

// ---- Stage 2: per-bucket CSR sort + deg/norm/row_start (LDS-staged) ----
__global__ void __launch_bounds__(256) fill2_kernel(
        const int* __restrict__ bucket_cur, uint* __restrict__ csr,
        int* __restrict__ row_start, int* __restrict__ degp,
        float* __restrict__ norm, int n_nodes) {
    __shared__ uint sbin[STRIDE];  // 11.5 KB
    __shared__ int deg[BNODES];
    __shared__ int rs[BNODES];
    __shared__ int cur[BNODES];
    int b = blockIdx.x;
    int t = threadIdx.x;
    int cnt = bucket_cur[b];
    if (cnt > STRIDE) cnt = STRIDE;
    size_t gbase = (size_t)b * STRIDE;

    for (int k = t; k < cnt; k += 256) sbin[k] = csr[gbase + k];
    if (t < BNODES) deg[t] = 0;
    __syncthreads();
    for (int k = t; k < cnt; k += 256) atomicAdd(&deg[sbin[k] & BMASK], 1);
    __syncthreads();

    int v = 0;
    if (t < BNODES) {
        v = deg[t];
        rs[t] = v;
    }
    __syncthreads();
    for (int o = 1; o < BNODES; o <<= 1) {
        int a = (t < BNODES && t >= o) ? rs[t - o] : 0;
        __syncthreads();
        if (t < BNODES) rs[t] += a;
        __syncthreads();
    }
    if (t < BNODES) {
        int excl = rs[t] - v;
        rs[t] = excl;
        cur[t] = 0;
        int node = b * BNODES + t;
        if (node < n_nodes) {
            row_start[node] = (int)gbase + excl;
            degp[node] = v;
            norm[node] = rsqrtf(fmaxf((float)v, 1.0f));
        }
    }
    __syncthreads();

    for (int k = t; k < cnt; k += 256) {
        uint p = sbin[k];
        int dl = p & BMASK;
        int r = atomicAdd(&cur[dl], 1);
        csr[gbase + rs[dl] + r] = p >> BSHIFT;  // plain src index
    }
}

// ---- Stage 3: gather: out[i] = norm_i * (sum norm_src * g_raw[src]) + bias --
#define UNPACK_FMA(u, nmv)                                   \
    acc[0] += __uint_as_float((u).x << 16) * (nmv);          \
    acc[1] += __uint_as_float((u).x & 0xffff0000u) * (nmv);  \
    acc[2] += __uint_as_float((u).y << 16) * (nmv);          \
    acc[3] += __uint_as_float((u).y & 0xffff0000u) * (nmv);  \
    acc[4] += __uint_as_float((u).z << 16) * (nmv);          \
    acc[5] += __uint_as_float((u).z & 0xffff0000u) * (nmv);  \
    acc[6] += __uint_as_float((u).w << 16) * (nmv);          \
    acc[7] += __uint_as_float((u).w & 0xffff0000u) * (nmv);

__global__ void __launch_bounds__(256) gather_out_kernel(
        const uint4* __restrict__ g128, const uint* __restrict__ csr,
        const int* __restrict__ row_start, const int* __restrict__ degp,
        const float* __restrict__ norm, const float* __restrict__ bias,
        float* __restrict__ out, int n) {
    int lane = threadIdx.x & 63;
    int wid = threadIdx.x >> 6;
    int i = blockIdx.x * 4 + wid;
    if (i >= n) return;
    int g = lane >> 4;
    int c = lane & 15;
    float4 b_lo = *(const float4*)(bias + 8 * c);
    float4 b_hi = *(const float4*)(bias + 8 * c + 4);

    int beg = row_start[i];
    int dv = degp[i];
    int end = beg + dv;
    float acc[8];
#pragma unroll
    for (int j = 0; j < 8; ++j) acc[j] = 0.f;

    for (int base = beg; base < end; base += 64) {
        int nk = end - base;
        if (nk > 64) nk = 64;
        int epre = (base + lane < end) ? (int)csr[base + lane] : 0;
        float npre = norm[epre];  // L2-resident; invalid lanes read node 0
        int k = 0;
        int kfull = nk & ~7;
        for (; k < kfull; k += 8) {  // 8 edges: 2 uint4 chains in flight
            int s0 = __shfl(epre, k + g, 64);
            int s1 = __shfl(epre, k + 4 + g, 64);
            float nm0 = __shfl(npre, k + g, 64);
            float nm1 = __shfl(npre, k + 4 + g, 64);
            uint4 u0 = g128[(size_t)s0 * 16 + c];
            uint4 u1 = g128[(size_t)s1 * 16 + c];
            UNPACK_FMA(u0, nm0);
            UNPACK_FMA(u1, nm1);
        }
        if (k < nk) {  // tail <8 edges, predicated per 16-lane group
            int e0 = k + g;
            int e1 = k + 4 + g;
            int s0 = __shfl(epre, e0 & 63, 64);
            int s1 = __shfl(epre, e1 & 63, 64);
            float nm0 = __shfl(npre, e0 & 63, 64);
            float nm1 = __shfl(npre, e1 & 63, 64);
            uint4 z = {0u, 0u, 0u, 0u};
            uint4 u0 = (e0 < nk) ? g128[(size_t)s0 * 16 + c] : z;
            uint4 u1 = (e1 < nk) ? g128[(size_t)s1 * 16 + c] : z;
            UNPACK_FMA(u0, nm0);
            UNPACK_FMA(u1, nm1);
        }
    }

#pragma unroll
    for (int j = 0; j < 8; ++j) {  // merge the 4 edge-subgroups
        acc[j] += __shfl_xor(acc[j], 16, 64);
        acc[j] += __shfl_xor(acc[j], 32, 64);
    }
    if (g == 0) {
        float nrm = rsqrtf(fmaxf((float)dv, 1.0f));
        float4 lo, hi;
        lo.x = acc[0] * nrm + b_lo.x;
        lo.y = acc[1] * nrm + b_lo.y;
        lo.z = acc[2] * nrm + b_lo.z;
        lo.w = acc[3] * nrm + b_lo.w;
        hi.x = acc[4] * nrm + b_hi.x;
        hi.y = acc[5] * nrm + b_hi.y;
        hi.z = acc[6] * nrm + b_hi.z;
        hi.w = acc[7] * nrm + b_hi.w;
        float* orow = out + (size_t)i * D + 8 * c;
        *(float4*)orow = lo;
        *(float4*)(orow + 4) = hi;
    }
}

extern "C" void kernel_launch(void* const* d_in, const int* in_sizes, int n_in,
                              void* d_out, int out_size, void* d_ws, size_t ws_size,
                              hipStream_t stream) {
    const float* feat   = (const float*)d_in[0];
    const float* weight = (const float*)d_in[1];
    const float* bias   = (const float*)d_in[2];
    const int*   src    = (const int*)d_in[3];
    const int*   dst    = (const int*)d_in[4];
    float* out = (float*)d_out;

    int n_nodes = in_sizes[0] / D;
    int n_edges = in_sizes[3];
    int nb = (n_nodes + BNODES - 1) >> BSHIFT;               // 782 buckets
    int nchunks = (n_edges + BIN_CHUNK - 1) / BIN_CHUNK;     // 782
    int ngemm = (n_nodes + GP_ROWS - 1) / GP_ROWS;           // 1563

    // workspace (4B elems): norm | deg | row_start | bucket_cur | csr | g32 | wpack
    float* norm       = (float*)d_ws;                    // n
    int*   degp       = (int*)(norm + n_nodes);          // n
    int*   row_start  = degp + n_nodes;                  // n
    int*   bucket_cur = row_start + n_nodes;             // NB_MAX
    uint*  csr        = (uint*)(bucket_cur + NB_MAX);    // nb*STRIDE (~9.2 MB)
    uint*  g32        = csr + (size_t)nb * STRIDE;       // 64n (25.6 MB)
    uint4* wpack      = (uint4*)(g32 + (size_t)n_nodes * 64);  // 32 KB

    init_kernel<<<2, 256, 0, stream>>>(bucket_cur, weight, wpack);
    mega_kernel<<<nchunks + ngemm, 256, 0, stream>>>(
        src, dst, bucket_cur, csr, feat, wpack, g32, n_edges, nchunks, ngemm,
        n_nodes);
    fill2_kernel<<<nb, 256, 0, stream>>>(bucket_cur, csr, row_start, degp, norm,
                                         n_nodes);
    gather_out_kernel<<<(n_nodes + 3) / 4, 256, 0, stream>>>(
        (const uint4*)g32, csr, row_start, degp, norm, bias, out, n_nodes);
}